// Round 7
// baseline (7161.146 us; speedup 1.0000x reference)
//
#include <hip/hip_runtime.h>
#include <math.h>

#define B_    32768
#define T_    128
#define OUT_  5
#define EPS_  1e-5f

typedef float f32x4 __attribute__((ext_vector_type(4)));
typedef __bf16 bfrag __attribute__((ext_vector_type(8)));
typedef unsigned short ushort_t;

// ---- workspace layout (float offsets) — unchanged verified layout ----
#define WS_WC2   0
#define WS_GB    67584
#define WS_A0    68112
#define WS_A1    84496
#define WS_C     100880
#define WS_IST   117264
#define WS_ZST   117904

__device__ __forceinline__ ushort_t f2bf(float f) {  // RNE
  unsigned u = __float_as_uint(f);
  u += 0x7FFFu + ((u >> 16) & 1u);
  return (ushort_t)(u >> 16);
}
__device__ __forceinline__ unsigned cvtpk(float lo, float hi) {  // RNE pack, 1 inst
  unsigned r;
  asm("v_cvt_pk_bf16_f32 %0, %1, %2" : "=v"(r) : "v"(lo), "v"(hi));
  return r;
}

// ---- kernel 1: per-timestep input moments (verified) ----
__global__ void k_istats(const float* __restrict__ x, float* __restrict__ istats) {
  const int tid = threadIdx.x;
  const int t = tid >> 1;
  const int i = tid & 1;
  const long b0 = (long)blockIdx.x * 64;
  float s_v = 0.f, s_vv = 0.f, s_cross = 0.f;
  for (int s = 0; s < 64; ++s) {
    float v = x[(b0 + s) * 256 + tid];
    float p = __shfl_xor(v, 1);
    s_v += v; s_vv += v * v; s_cross += v * p;
  }
  float* st = istats + t * 5;
  if (i == 0) {
    atomicAdd(st + 0, s_v); atomicAdd(st + 2, s_vv); atomicAdd(st + 4, s_cross);
  } else {
    atomicAdd(st + 1, s_v); atomicAdd(st + 3, s_vv);
  }
}

// ---- kernel 2: pack weights to fragment-ordered bf16 Wc2 + gbias (verified) ----
__global__ void k_prep_w(const float* __restrict__ w_ih, const float* __restrict__ w_hh,
                         const float* __restrict__ w_out, const float* __restrict__ b_ih,
                         const float* __restrict__ b_hh, const float* __restrict__ b_out,
                         ushort_t* __restrict__ Wc2, float* __restrict__ gbias) {
  int idx = blockIdx.x * 256 + threadIdx.x;  // 0 .. 135167
  int e = idx & 7;
  int lm = (idx >> 3) & 15;
  int lq = (idx >> 7) & 3;
  int ks = (idx >> 9) & 7;
  int T = idx >> 12;
  int k = ks * 32 + lq * 8 + e;
  float v;
  if (T < 32) {
    int g = T * 16 + lm;  // row = gate*128 + cell
    v = (k < 128) ? w_ih[g * 128 + k] : w_hh[g * 128 + (k - 128)];
  } else {
    v = (k >= 128 && lm < OUT_) ? w_out[lm * 128 + (k - 128)] : 0.f;
  }
  Wc2[idx] = f2bf(v);
  if (idx < 528) {
    float bv = (idx < 512) ? b_ih[idx] + b_hh[idx]
                           : (idx < 517 ? b_out[idx - 512] : 0.f);
    gbias[idx] = bv;
  }
}

// ---- kernel 3: fold embed linear + BN into per-(t,f) affine coeffs (verified) ----
__global__ void k_coef(const float* __restrict__ istats, const float* __restrict__ w_emb,
                       const float* __restrict__ b_emb, const float* __restrict__ gamma1,
                       const float* __restrict__ beta1, float* __restrict__ A0,
                       float* __restrict__ A1, float* __restrict__ C) {
  int idx = blockIdx.x * 256 + threadIdx.x;  // 0 .. 16383
  int t = idx >> 7, f = idx & 127;
  const float* st = istats + t * 5;
  const float invB = 1.f / (float)B_;
  float m0 = st[0] * invB, m1 = st[1] * invB;
  float v00 = st[2] * invB - m0 * m0;
  float v11 = st[3] * invB - m1 * m1;
  float c01 = st[4] * invB - m0 * m1;
  float w0 = w_emb[f * 2 + 0], w1 = w_emb[f * 2 + 1];
  float mu = m0 * w0 + m1 * w1 + b_emb[f];
  float var = w0 * w0 * v00 + w1 * w1 * v11 + 2.f * w0 * w1 * c01;
  float alpha = gamma1[f] * rsqrtf(var + EPS_);
  A0[t * 128 + f] = alpha * w0;
  A1[t * 128 + f] = alpha * w1;
  C[t * 128 + f] = alpha * (b_emb[f] - mu) + beta1[f];
}

// ---- kernel 4: MFMA recurrent LSTM — OCCUPANCY-DOUBLED (64 samples/block) ----
// 512 blocks x 512 threads, 64 samples/block, __launch_bounds__(512,4):
// LDS 78 KB/block -> 2 blocks/CU -> 4 waves/SIMD (was 1 block, 2 waves/SIMD).
// Six schedule variants plateaued at ~1.5 ms because 2 waves/SIMD cannot cover
// queued LDS latency in the GATE phase; per-CU pipe totals (LDS ~8K cyc/t,
// trans ~5K, matrix ~2.6K) imply a ~10K cyc/t overlap floor. This version
// changes ONLY parallelism: per-CU work identical, 2 independent blocks drift
// out of phase so one covers the other's barrier/LDS stalls. Register budget
// for the 4-wave pools (<=128 VGPR + <=128 AGPR): gate weights = exactly 128
// (AGPR); z-weights demoted to LDS (constant, 4 reads/t on z-waves only);
// mt loop 8 -> 4 halves acc/cst pressure. z handled by waves 0-3 via the
// pre-existing mt==w guard (mt<4 auto-excludes w>=4).
#define GATE_TILE(MT, PB)                                                         \
  {                                                                               \
    const ushort_t* arow_ = &Abuf[(MT) * 16 + lm][0];                             \
    _Pragma("unroll")                                                             \
    for (int i = 0; i < 4; ++i) {                                                 \
      f32x4 v_ = {bias_g[i], bias_g[i], bias_g[i], bias_g[i]};                    \
      acc[PB][i] = v_;                                                            \
    }                                                                             \
    _Pragma("unroll")                                                             \
    for (int ks = 0; ks < 8; ++ks) {                                              \
      const int col_ = (ks < 4 ? pe + ks * 32 : ph + (ks - 4) * 32) + lq * 8;     \
      const bfrag Af_ = __builtin_bit_cast(bfrag, *(const uint4*)(arow_ + col_)); \
      _Pragma("unroll")                                                           \
      for (int i = 0; i < 4; ++i)                                                 \
        acc[PB][i] = __builtin_amdgcn_mfma_f32_16x16x32_bf16(                     \
            Af_, __builtin_bit_cast(bfrag, wreg[i][ks]), acc[PB][i], 0, 0, 0);    \
    }                                                                             \
    if ((MT) == w && t > 0) {                                                     \
      const ushort_t* hrow_ = &Abuf[w * 16 + lm][0];                              \
      f32x4 z_ = {bias_z, bias_z, bias_z, bias_z};                                \
      _Pragma("unroll")                                                           \
      for (int i = 0; i < 4; ++i) {                                               \
        const bfrag Ah_ = __builtin_bit_cast(                                     \
            bfrag, *(const uint4*)(hrow_ + ph + i * 32 + lq * 8));                \
        const bfrag Wz_ = __builtin_bit_cast(bfrag, wzLds[i][l]);                 \
        z_ = __builtin_amdgcn_mfma_f32_16x16x32_bf16(Ah_, Wz_, z_, 0, 0, 0);      \
      }                                                                           \
      zac = z_;                                                                   \
    }                                                                             \
  }

#define EW_TILE(MT, PB)                                                           \
  {                                                                               \
    if ((MT) == w && t > 0) {                                                     \
      float sz_ = 0.f, sq_ = 0.f;                                                 \
      _Pragma("unroll")                                                           \
      for (int r = 0; r < 4; ++r) {                                               \
        const float zv_ = zac[r];                                                 \
        sz_ += zv_; sq_ += zv_ * zv_;                                             \
      }                                                                           \
      sz_ += __shfl_xor(sz_, 16); sz_ += __shfl_xor(sz_, 32);                     \
      sq_ += __shfl_xor(sq_, 16); sq_ += __shfl_xor(sq_, 32);                     \
      if (lq == 0 && lm < OUT_) { zredS[p][w][lm] = sz_; zredQ[p][w][lm] = sq_; } \
      if (((t - 1) & 1) == 0) {                                                   \
        zh0 = zac;                                                                \
      } else {                                                                    \
        zh1 = zac;                                                                \
        if (lm < OUT_) {                                                          \
          const size_t sb0_ = (size_t)(b0 + (w << 4) + lq * 4) * (T_ * OUT_) +    \
                              (size_t)(t - 2) * OUT_ + lm;                        \
          _Pragma("unroll")                                                       \
          for (int r = 0; r < 4; ++r) {                                           \
            const size_t sb_ = sb0_ + (size_t)r * (T_ * OUT_);                    \
            out[sb_] = zh0[r];                                                    \
            out[sb_ + OUT_] = zh1[r];                                             \
          }                                                                       \
        }                                                                         \
      }                                                                           \
    }                                                                             \
    if (t < T_) {                                                                 \
      float ei_[4], ef_[4], eg_[4], eo_[4];                                       \
      _Pragma("unroll")                                                           \
      for (int r = 0; r < 4; ++r) {                                               \
        ei_[r] = __expf(-acc[PB][0][r]);                                          \
        ef_[r] = __expf(-acc[PB][1][r]);                                          \
        eg_[r] = __expf(2.f * acc[PB][2][r]);                                     \
        eo_[r] = __expf(-acc[PB][3][r]);                                          \
      }                                                                           \
      float ig_[4], fg_[4], tg_[4], og_[4];                                       \
      _Pragma("unroll")                                                           \
      for (int r = 0; r < 4; ++r) {                                               \
        ig_[r] = __builtin_amdgcn_rcpf(1.f + ei_[r]);                             \
        fg_[r] = __builtin_amdgcn_rcpf(1.f + ef_[r]);                             \
        tg_[r] = 1.f - 2.f * __builtin_amdgcn_rcpf(1.f + eg_[r]);                 \
        og_[r] = __builtin_amdgcn_rcpf(1.f + eo_[r]);                             \
      }                                                                           \
      float eh_[4];                                                               \
      _Pragma("unroll")                                                           \
      for (int r = 0; r < 4; ++r) {                                               \
        const float cn_ = fmaf(fg_[r], cst[MT][r], ig_[r] * tg_[r]);              \
        cst[MT][r] = cn_;                                                         \
        eh_[r] = __expf(2.f * cn_);                                               \
      }                                                                           \
      _Pragma("unroll")                                                           \
      for (int r = 0; r < 4; ++r) {                                               \
        const float th_ = 1.f - 2.f * __builtin_amdgcn_rcpf(1.f + eh_[r]);        \
        const float h_ = og_[r] * th_;                                            \
        Abuf[(MT) * 16 + lq * 4 + r][hw + (w << 4) + lm] =                        \
            (ushort_t)cvtpk(h_, h_);                                              \
      }                                                                           \
    }                                                                             \
  }

__global__ __launch_bounds__(512, 4) void k_lstm(
    const float* __restrict__ x, const ushort_t* __restrict__ Wc2,
    const float* __restrict__ gbias, const float* __restrict__ A0,
    const float* __restrict__ A1, const float* __restrict__ Cc,
    float* __restrict__ out, float* __restrict__ zstats) {
  // Row = sample (64). Cols (ushort): [0,128) E0 | [128,256) E1 |
  // [256,384) H0 | [384,512) H1 ; row stride 520 ushort = 1040 B.
  __shared__ __align__(16) ushort_t Abuf[64][520];      // 66,560 B
  // coef windows: 2 bufs x 2 t x 16 chunks x 28 floats; 7,168 B
  __shared__ __align__(16) float CoefW[2][2 * 16 * 28];
  __shared__ __align__(16) uint4 wzLds[4][64];          // 4,096 B z-weights
  __shared__ float zredS[2][4][5], zredQ[2][4][5];

  const int tid = threadIdx.x;
  const int w = tid >> 6;   // wave 0..7
  const int l = tid & 63;
  const int lm = l & 15;    // MFMA lane col
  const int lq = l >> 4;    // MFMA quad
  const long b0 = (long)blockIdx.x * 64;

  const uint4* W4 = (const uint4*)Wc2;

  // persistent gate weights: exactly 128 regs (AGPR pool), loaded once
  uint4 wreg[4][8];
#pragma unroll
  for (int i = 0; i < 4; ++i)
#pragma unroll
    for (int ks = 0; ks < 8; ++ks)
      wreg[i][ks] = W4[((w + 8 * i) * 8 + ks) * 64 + l];

  float bias_g[4];
#pragma unroll
  for (int i = 0; i < 4; ++i) bias_g[i] = gbias[(w + 8 * i) * 16 + lm];
  const float bias_z = gbias[512 + lm];

  // staging roles: thread owns rows {2rg, 2rg+1}, f-chunk cc
  const int cc = tid & 15;
  const int rg = tid >> 4;           // 0..31
  const float2* x2 = (const float2*)x;

  // window-load descriptors (threads 0..191 load 192 f32x4 per 2-t window)
  const bool wl_on = (tid < 192);
  const int wl_tw = tid / 96;        // t-slice within window (0..1)
  const int wl_q = tid - wl_tw * 96;
  const int wl_cc = wl_q / 6;
  const int wl_part = wl_q - wl_cc * 6;  // 0,1:a0  2,3:a1  4,5:c
  const float* wl_src =
      (wl_part < 2 ? A0 : (wl_part < 4 ? A1 : Cc)) + wl_cc * 8 + (wl_part & 1) * 4;
  const int wl_dst = wl_tw * 448 + wl_cc * 28 + wl_part * 4;

  float cst[4][4];
#pragma unroll
  for (int mt = 0; mt < 4; ++mt)
#pragma unroll
    for (int r = 0; r < 4; ++r) cst[mt][r] = 0.f;

  f32x4 zh0 = {0.f, 0.f, 0.f, 0.f}, zh1 = zh0;

  // zero Abuf (h(-1)=0; rest don't-care)
  for (int i = tid; i < 64 * 520 / 8; i += 512)
    ((uint4*)&Abuf[0][0])[i] = make_uint4(0u, 0u, 0u, 0u);
  // z-weights -> LDS (constant across t)
  if (tid < 256) wzLds[tid >> 6][tid & 63] = W4[(32 * 8 + 4 + (tid >> 6)) * 64 + (tid & 63)];
  // prologue: coef window (t=0,1) -> buf 0 ; x(0) rows -> registers
  if (wl_on)
    *(f32x4*)(&CoefW[0][0] + wl_dst) = *(const f32x4*)(wl_src + wl_tw * 128);
  float2 xv2[2];
#pragma unroll
  for (int r = 0; r < 2; ++r) xv2[r] = x2[(size_t)(b0 + rg * 2 + r) * 128 + 0];
  __syncthreads();

  for (int t = 0; t <= T_; ++t) {
    const int p = t & 1;
    const int pe = p * 128;              // E region for e(t)
    const int ph = 256 + (p ^ 1) * 128;  // H region holding h(t-1)
    const int hw = 256 + p * 128;        // H region receiving h(t)

    // ---- pre-barrier: stage e(t) from LDS coefs + registered x (no VMEM) ----
    if (t < T_) {
      const float* cf = &CoefW[(t >> 1) & 1][(t & 1) * 448 + cc * 28];
      const f32x4 a0l = *(const f32x4*)(cf);
      const f32x4 a0h = *(const f32x4*)(cf + 4);
      const f32x4 a1l = *(const f32x4*)(cf + 8);
      const f32x4 a1h = *(const f32x4*)(cf + 12);
      const f32x4 ccl = *(const f32x4*)(cf + 16);
      const f32x4 cch = *(const f32x4*)(cf + 20);
#pragma unroll
      for (int r = 0; r < 2; ++r) {
        const float2 xv = xv2[r];
        unsigned pk[4];
#pragma unroll
        for (int j = 0; j < 2; ++j) {
          float e0 = fmaf(xv.x, a0l[2 * j],     fmaf(xv.y, a1l[2 * j],     ccl[2 * j]));
          float e1 = fmaf(xv.x, a0l[2 * j + 1], fmaf(xv.y, a1l[2 * j + 1], ccl[2 * j + 1]));
          pk[j] = cvtpk(fmaxf(e0, 0.f), fmaxf(e1, 0.f));
          float e2 = fmaf(xv.x, a0h[2 * j],     fmaf(xv.y, a1h[2 * j],     cch[2 * j]));
          float e3 = fmaf(xv.x, a0h[2 * j + 1], fmaf(xv.y, a1h[2 * j + 1], cch[2 * j + 1]));
          pk[2 + j] = cvtpk(fmaxf(e2, 0.f), fmaxf(e3, 0.f));
        }
        *(uint4*)&Abuf[rg * 2 + r][pe + cc * 8] = make_uint4(pk[0], pk[1], pk[2], pk[3]);
      }
      // every 2nd t: load next 2-t coef window into the idle buffer
      if ((t & 1) == 1 && t + 1 < T_ && wl_on) {
        const int t1 = t + 1;  // even
        *(f32x4*)(&CoefW[(t1 >> 1) & 1][0] + wl_dst) =
            *(const f32x4*)(wl_src + (t1 + wl_tw) * 128);
      }
    }
    __syncthreads();  // the ONLY barrier per timestep: e(t) + h(t-1) visible

    // prefetch x(t+1): full compute phase of latency cover
    if (t + 1 < T_) {
#pragma unroll
      for (int r = 0; r < 2; ++r)
        xv2[r] = x2[(size_t)(b0 + rg * 2 + r) * 128 + (t + 1)];
    }

    // deferred cross-wave z-stat flush: ts t-2 from buffer p^1 (written iter t-1)
    if (t >= 2 && tid < 10) {
      const int o = tid >> 1, kind = tid & 1;
      float s = 0.f;
#pragma unroll
      for (int ww = 0; ww < 4; ++ww)
        s += kind ? zredQ[p ^ 1][ww][o] : zredS[p ^ 1][ww][o];
      atomicAdd(&zstats[(size_t)(t - 2) * 10 + o * 2 + kind], s);
    }

    // ---- software-pipelined mt loop: GATE(mt) overlaps EW(mt-1) ----
    f32x4 acc[2][4];
    f32x4 zac = {0.f, 0.f, 0.f, 0.f};
    GATE_TILE(0, 0)
#pragma unroll
    for (int mt = 1; mt < 4; ++mt) {
      GATE_TILE(mt, (mt & 1))
      EW_TILE((mt - 1), ((mt - 1) & 1))
    }
    EW_TILE(3, 1)
  }

  // final z-stat flush: ts T_-1 written at iter T_ into buffer (T_&1)=0
  __syncthreads();
  if (tid < 10) {
    const int o = tid >> 1, kind = tid & 1;
    float s = 0.f;
#pragma unroll
    for (int ww = 0; ww < 4; ++ww) s += kind ? zredQ[0][ww][o] : zredS[0][ww][o];
    atomicAdd(&zstats[(size_t)(T_ - 1) * 10 + o * 2 + kind], s);
  }
}

// ---- kernel 5: in-place output BN + ReLU (verified) ----
__global__ void k_outbn(float* __restrict__ out, const float* __restrict__ zstats,
                        const float* __restrict__ gamma2, const float* __restrict__ beta2) {
  int idx = blockIdx.x * 256 + threadIdx.x;
  int r = idx % 640;
  int t = r / 5, o = r - t * 5;
  float z = out[idx];
  float sum = zstats[t * 10 + o * 2];
  float ss = zstats[t * 10 + o * 2 + 1];
  float mu = sum * (1.f / (float)B_);
  float var = ss * (1.f / (float)B_) - mu * mu;
  float y = gamma2[o] * (z - mu) * rsqrtf(var + EPS_) + beta2[o];
  out[idx] = fmaxf(y, 0.f);
}

extern "C" void kernel_launch(void* const* d_in, const int* in_sizes, int n_in, void* d_out,
                              int out_size, void* d_ws, size_t ws_size, hipStream_t stream) {
  const float* x = (const float*)d_in[0];
  const float* w_emb = (const float*)d_in[1];
  const float* b_emb = (const float*)d_in[2];
  const float* gamma1 = (const float*)d_in[3];
  const float* beta1 = (const float*)d_in[4];
  const float* w_ih = (const float*)d_in[5];
  const float* w_hh = (const float*)d_in[6];
  const float* b_ih = (const float*)d_in[7];
  const float* b_hh = (const float*)d_in[8];
  const float* w_out = (const float*)d_in[9];
  const float* b_out = (const float*)d_in[10];
  const float* gamma2 = (const float*)d_in[11];
  const float* beta2 = (const float*)d_in[12];
  float* out = (float*)d_out;
  float* ws = (float*)d_ws;

  ushort_t* Wc2 = (ushort_t*)(ws + WS_WC2);
  float* gbias = ws + WS_GB;
  float* A0 = ws + WS_A0;
  float* A1 = ws + WS_A1;
  float* C = ws + WS_C;
  float* istats = ws + WS_IST;
  float* zstats = ws + WS_ZST;

  hipMemsetAsync(istats, 0, 640 * sizeof(float), stream);
  hipMemsetAsync(zstats, 0, 1280 * sizeof(float), stream);

  k_istats<<<512, 256, 0, stream>>>(x, istats);
  k_prep_w<<<528, 256, 0, stream>>>(w_ih, w_hh, w_out, b_ih, b_hh, b_out, Wc2, gbias);
  k_coef<<<64, 256, 0, stream>>>(istats, w_emb, b_emb, gamma1, beta1, A0, A1, C);
  k_lstm<<<512, 512, 0, stream>>>(x, Wc2, gbias, A0, A1, C, out, zstats);
  k_outbn<<<(B_ * T_ * OUT_) / 256, 256, 0, stream>>>(out, zstats, gamma2, beta2);
}

// Round 8
// 1464.585 us; speedup vs baseline: 4.8895x; 4.8895x over previous
//
#include <hip/hip_runtime.h>
#include <math.h>

#define B_    32768
#define T_    128
#define OUT_  5
#define EPS_  1e-5f

typedef float f32x4 __attribute__((ext_vector_type(4)));
typedef __bf16 bfrag __attribute__((ext_vector_type(8)));
typedef unsigned short ushort_t;

// ---- workspace layout (float offsets) — unchanged verified layout ----
#define WS_WC2   0
#define WS_GB    67584
#define WS_A0    68112
#define WS_A1    84496
#define WS_C     100880
#define WS_IST   117264
#define WS_ZST   117904

__device__ __forceinline__ ushort_t f2bf(float f) {  // RNE
  unsigned u = __float_as_uint(f);
  u += 0x7FFFu + ((u >> 16) & 1u);
  return (ushort_t)(u >> 16);
}
__device__ __forceinline__ unsigned cvtpk(float lo, float hi) {  // RNE pack, 1 inst
  unsigned r;
  asm("v_cvt_pk_bf16_f32 %0, %1, %2" : "=v"(r) : "v"(lo), "v"(hi));
  return r;
}

// ---- kernel 1: per-timestep input moments (verified) ----
__global__ void k_istats(const float* __restrict__ x, float* __restrict__ istats) {
  const int tid = threadIdx.x;
  const int t = tid >> 1;
  const int i = tid & 1;
  const long b0 = (long)blockIdx.x * 64;
  float s_v = 0.f, s_vv = 0.f, s_cross = 0.f;
  for (int s = 0; s < 64; ++s) {
    float v = x[(b0 + s) * 256 + tid];
    float p = __shfl_xor(v, 1);
    s_v += v; s_vv += v * v; s_cross += v * p;
  }
  float* st = istats + t * 5;
  if (i == 0) {
    atomicAdd(st + 0, s_v); atomicAdd(st + 2, s_vv); atomicAdd(st + 4, s_cross);
  } else {
    atomicAdd(st + 1, s_v); atomicAdd(st + 3, s_vv);
  }
}

// ---- kernel 2: pack weights to fragment-ordered bf16 Wc2 + gbias (verified) ----
__global__ void k_prep_w(const float* __restrict__ w_ih, const float* __restrict__ w_hh,
                         const float* __restrict__ w_out, const float* __restrict__ b_ih,
                         const float* __restrict__ b_hh, const float* __restrict__ b_out,
                         ushort_t* __restrict__ Wc2, float* __restrict__ gbias) {
  int idx = blockIdx.x * 256 + threadIdx.x;  // 0 .. 135167
  int e = idx & 7;
  int lm = (idx >> 3) & 15;
  int lq = (idx >> 7) & 3;
  int ks = (idx >> 9) & 7;
  int T = idx >> 12;
  int k = ks * 32 + lq * 8 + e;
  float v;
  if (T < 32) {
    int g = T * 16 + lm;  // row = gate*128 + cell
    v = (k < 128) ? w_ih[g * 128 + k] : w_hh[g * 128 + (k - 128)];
  } else {
    v = (k >= 128 && lm < OUT_) ? w_out[lm * 128 + (k - 128)] : 0.f;
  }
  Wc2[idx] = f2bf(v);
  if (idx < 528) {
    float bv = (idx < 512) ? b_ih[idx] + b_hh[idx]
                           : (idx < 517 ? b_out[idx - 512] : 0.f);
    gbias[idx] = bv;
  }
}

// ---- kernel 3: fold embed linear + BN into per-(t,f) affine coeffs (verified) ----
__global__ void k_coef(const float* __restrict__ istats, const float* __restrict__ w_emb,
                       const float* __restrict__ b_emb, const float* __restrict__ gamma1,
                       const float* __restrict__ beta1, float* __restrict__ A0,
                       float* __restrict__ A1, float* __restrict__ C) {
  int idx = blockIdx.x * 256 + threadIdx.x;  // 0 .. 16383
  int t = idx >> 7, f = idx & 127;
  const float* st = istats + t * 5;
  const float invB = 1.f / (float)B_;
  float m0 = st[0] * invB, m1 = st[1] * invB;
  float v00 = st[2] * invB - m0 * m0;
  float v11 = st[3] * invB - m1 * m1;
  float c01 = st[4] * invB - m0 * m1;
  float w0 = w_emb[f * 2 + 0], w1 = w_emb[f * 2 + 1];
  float mu = m0 * w0 + m1 * w1 + b_emb[f];
  float var = w0 * w0 * v00 + w1 * w1 * v11 + 2.f * w0 * w1 * c01;
  float alpha = gamma1[f] * rsqrtf(var + EPS_);
  A0[t * 128 + f] = alpha * w0;
  A1[t * 128 + f] = alpha * w1;
  C[t * 128 + f] = alpha * (b_emb[f] - mu) + beta1[f];
}

// ---- kernel 4: MFMA recurrent LSTM — RESTORED R6 (best measured: 1478.9 us) ----
// 256 blocks x 512 threads (8 waves), 128 samples/block, 2 waves/SIMD
// (register-locked: 128 VGPR + 128 AGPR weights = 256/wave, pool 512/SIMD —
// proven full by R7's spill collapse). Weights register-resident; coefs staged
// in LDS 4-t double-buffered windows; x prefetched post-barrier; one barrier/t;
// dual-acc 1-tile software pipeline; staging assigns each thread 4 rows x 1
// f-chunk (6 f32x4 coef reads/t). EW breadth-first 4-way ILP.
#define GATE_TILE(MT, PB)                                                         \
  {                                                                               \
    const ushort_t* arow_ = &Abuf[(MT) * 16 + lm][0];                             \
    _Pragma("unroll")                                                             \
    for (int i = 0; i < 4; ++i) {                                                 \
      f32x4 v_ = {bias_g[i], bias_g[i], bias_g[i], bias_g[i]};                    \
      acc[PB][i] = v_;                                                            \
    }                                                                             \
    _Pragma("unroll")                                                             \
    for (int ks = 0; ks < 8; ++ks) {                                              \
      const int col_ = (ks < 4 ? pe + ks * 32 : ph + (ks - 4) * 32) + lq * 8;     \
      const bfrag Af_ = __builtin_bit_cast(bfrag, *(const uint4*)(arow_ + col_)); \
      _Pragma("unroll")                                                           \
      for (int i = 0; i < 4; ++i)                                                 \
        acc[PB][i] = __builtin_amdgcn_mfma_f32_16x16x32_bf16(                     \
            Af_, __builtin_bit_cast(bfrag, wreg[i][ks]), acc[PB][i], 0, 0, 0);    \
    }                                                                             \
    if ((MT) == w && t > 0) {                                                     \
      const ushort_t* hrow_ = &Abuf[w * 16 + lm][0];                              \
      f32x4 z_ = {bias_z, bias_z, bias_z, bias_z};                                \
      _Pragma("unroll")                                                           \
      for (int i = 0; i < 4; ++i) {                                               \
        const bfrag Ah_ = __builtin_bit_cast(                                     \
            bfrag, *(const uint4*)(hrow_ + ph + i * 32 + lq * 8));                \
        z_ = __builtin_amdgcn_mfma_f32_16x16x32_bf16(                             \
            Ah_, __builtin_bit_cast(bfrag, wzr[i]), z_, 0, 0, 0);                 \
      }                                                                           \
      zac = z_;                                                                   \
    }                                                                             \
  }

#define EW_TILE(MT, PB)                                                           \
  {                                                                               \
    if ((MT) == w && t > 0) {                                                     \
      float sz_ = 0.f, sq_ = 0.f;                                                 \
      _Pragma("unroll")                                                           \
      for (int r = 0; r < 4; ++r) {                                               \
        const float zv_ = zac[r];                                                 \
        sz_ += zv_; sq_ += zv_ * zv_;                                             \
      }                                                                           \
      sz_ += __shfl_xor(sz_, 16); sz_ += __shfl_xor(sz_, 32);                     \
      sq_ += __shfl_xor(sq_, 16); sq_ += __shfl_xor(sq_, 32);                     \
      if (lq == 0 && lm < OUT_) { zredS[p][w][lm] = sz_; zredQ[p][w][lm] = sq_; } \
      if (((t - 1) & 1) == 0) {                                                   \
        zh0 = zac;                                                                \
      } else {                                                                    \
        zh1 = zac;                                                                \
        if (lm < OUT_) {                                                          \
          const size_t sb0_ = (size_t)(b0 + (w << 4) + lq * 4) * (T_ * OUT_) +    \
                              (size_t)(t - 2) * OUT_ + lm;                        \
          _Pragma("unroll")                                                       \
          for (int r = 0; r < 4; ++r) {                                           \
            const size_t sb_ = sb0_ + (size_t)r * (T_ * OUT_);                    \
            out[sb_] = zh0[r];                                                    \
            out[sb_ + OUT_] = zh1[r];                                             \
          }                                                                       \
        }                                                                         \
      }                                                                           \
    }                                                                             \
    if (t < T_) {                                                                 \
      float ei_[4], ef_[4], eg_[4], eo_[4];                                       \
      _Pragma("unroll")                                                           \
      for (int r = 0; r < 4; ++r) {                                               \
        ei_[r] = __expf(-acc[PB][0][r]);                                          \
        ef_[r] = __expf(-acc[PB][1][r]);                                          \
        eg_[r] = __expf(2.f * acc[PB][2][r]);                                     \
        eo_[r] = __expf(-acc[PB][3][r]);                                          \
      }                                                                           \
      float ig_[4], fg_[4], tg_[4], og_[4];                                       \
      _Pragma("unroll")                                                           \
      for (int r = 0; r < 4; ++r) {                                               \
        ig_[r] = __builtin_amdgcn_rcpf(1.f + ei_[r]);                             \
        fg_[r] = __builtin_amdgcn_rcpf(1.f + ef_[r]);                             \
        tg_[r] = 1.f - 2.f * __builtin_amdgcn_rcpf(1.f + eg_[r]);                 \
        og_[r] = __builtin_amdgcn_rcpf(1.f + eo_[r]);                             \
      }                                                                           \
      float eh_[4];                                                               \
      _Pragma("unroll")                                                           \
      for (int r = 0; r < 4; ++r) {                                               \
        const float cn_ = fmaf(fg_[r], cst[MT][r], ig_[r] * tg_[r]);              \
        cst[MT][r] = cn_;                                                         \
        eh_[r] = __expf(2.f * cn_);                                               \
      }                                                                           \
      _Pragma("unroll")                                                           \
      for (int r = 0; r < 4; ++r) {                                               \
        const float th_ = 1.f - 2.f * __builtin_amdgcn_rcpf(1.f + eh_[r]);        \
        const float h_ = og_[r] * th_;                                            \
        Abuf[(MT) * 16 + lq * 4 + r][hw + (w << 4) + lm] =                        \
            (ushort_t)cvtpk(h_, h_);                                              \
      }                                                                           \
    }                                                                             \
  }

__global__ __launch_bounds__(512, 2) void k_lstm(
    const float* __restrict__ x, const ushort_t* __restrict__ Wc2,
    const float* __restrict__ gbias, const float* __restrict__ A0,
    const float* __restrict__ A1, const float* __restrict__ Cc,
    float* __restrict__ out, float* __restrict__ zstats) {
  // Row = sample (128). Cols (ushort): [0,128) E0 | [128,256) E1 |
  // [256,384) H0 | [384,512) H1 ; row stride 520 ushort = 1040 B.
  __shared__ __align__(16) ushort_t Abuf[128][520];  // 133,120 B
  // coef windows: 2 bufs x 4 t x 16 chunks x 28 floats (24 used + 4 pad)
  // chunk layout: [a0 x8][a1 x8][c x8][pad x4]; stride 112 B => 2-way banks.
  __shared__ __align__(16) float CoefW[2][4 * 16 * 28];  // 14,336 B
  __shared__ float zredS[2][8][5], zredQ[2][8][5];

  const int tid = threadIdx.x;
  const int w = tid >> 6;   // wave 0..7
  const int l = tid & 63;
  const int lm = l & 15;    // MFMA lane col
  const int lq = l >> 4;    // MFMA quad
  const long b0 = (long)blockIdx.x * 128;

  const uint4* W4 = (const uint4*)Wc2;

  // persistent weights (loaded once; unified VGPR/AGPR file)
  uint4 wreg[4][8];
#pragma unroll
  for (int i = 0; i < 4; ++i)
#pragma unroll
    for (int ks = 0; ks < 8; ++ks)
      wreg[i][ks] = W4[((w + 8 * i) * 8 + ks) * 64 + l];
  uint4 wzr[4];
#pragma unroll
  for (int i = 0; i < 4; ++i) wzr[i] = W4[(32 * 8 + 4 + i) * 64 + l];

  float bias_g[4];
#pragma unroll
  for (int i = 0; i < 4; ++i) bias_g[i] = gbias[(w + 8 * i) * 16 + lm];
  const float bias_z = gbias[512 + lm];

  // staging roles: thread owns rows rg*4..rg*4+3, f-chunk cc (f = cc*8..cc*8+7)
  const int cc = tid & 15;
  const int rg = tid >> 4;           // 0..31 ; wave w covers rows [16w,16w+16)
  const float2* x2 = (const float2*)x;

  // tid-constant window-load descriptors (threads 0..383 load 384 f32x4/window)
  const bool wl_on = (tid < 384);
  const int wl_tw = tid / 96;        // t-slice within window
  const int wl_q = tid - wl_tw * 96;
  const int wl_cc = wl_q / 6;
  const int wl_part = wl_q - wl_cc * 6;  // 0,1:a0  2,3:a1  4,5:c
  const float* wl_src =
      (wl_part < 2 ? A0 : (wl_part < 4 ? A1 : Cc)) + wl_cc * 8 + (wl_part & 1) * 4;
  const int wl_dst = wl_tw * 448 + wl_cc * 28 + wl_part * 4;

  float cst[8][4];
#pragma unroll
  for (int mt = 0; mt < 8; ++mt)
#pragma unroll
    for (int r = 0; r < 4; ++r) cst[mt][r] = 0.f;

  f32x4 zh0 = {0.f, 0.f, 0.f, 0.f}, zh1 = zh0;

  // zero Abuf (h(-1)=0; rest don't-care)
  for (int i = tid; i < 128 * 520 / 8; i += 512)
    ((uint4*)&Abuf[0][0])[i] = make_uint4(0u, 0u, 0u, 0u);
  // prologue: coef window (t=0..3) -> buf 0 ; x(0) rows -> registers
  if (wl_on)
    *(f32x4*)(&CoefW[0][0] + wl_dst) = *(const f32x4*)(wl_src + wl_tw * 128);
  float2 xv4[4];
#pragma unroll
  for (int r = 0; r < 4; ++r) xv4[r] = x2[(size_t)(b0 + rg * 4 + r) * 128 + 0];
  __syncthreads();

  for (int t = 0; t <= T_; ++t) {
    const int p = t & 1;
    const int pe = p * 128;              // E region for e(t)
    const int ph = 256 + (p ^ 1) * 128;  // H region holding h(t-1)
    const int hw = 256 + p * 128;        // H region receiving h(t)

    // ---- pre-barrier: stage e(t) from LDS coefs + registered x (no VMEM) ----
    if (t < T_) {
      const float* cf = &CoefW[(t >> 2) & 1][(t & 3) * 448 + cc * 28];
      const f32x4 a0l = *(const f32x4*)(cf);
      const f32x4 a0h = *(const f32x4*)(cf + 4);
      const f32x4 a1l = *(const f32x4*)(cf + 8);
      const f32x4 a1h = *(const f32x4*)(cf + 12);
      const f32x4 ccl = *(const f32x4*)(cf + 16);
      const f32x4 cch = *(const f32x4*)(cf + 20);
#pragma unroll
      for (int r = 0; r < 4; ++r) {
        const float2 xv = xv4[r];
        unsigned pk[4];
#pragma unroll
        for (int j = 0; j < 2; ++j) {
          float e0 = fmaf(xv.x, a0l[2 * j],     fmaf(xv.y, a1l[2 * j],     ccl[2 * j]));
          float e1 = fmaf(xv.x, a0l[2 * j + 1], fmaf(xv.y, a1l[2 * j + 1], ccl[2 * j + 1]));
          pk[j] = cvtpk(fmaxf(e0, 0.f), fmaxf(e1, 0.f));
          float e2 = fmaf(xv.x, a0h[2 * j],     fmaf(xv.y, a1h[2 * j],     cch[2 * j]));
          float e3 = fmaf(xv.x, a0h[2 * j + 1], fmaf(xv.y, a1h[2 * j + 1], cch[2 * j + 1]));
          pk[2 + j] = cvtpk(fmaxf(e2, 0.f), fmaxf(e3, 0.f));
        }
        *(uint4*)&Abuf[rg * 4 + r][pe + cc * 8] = make_uint4(pk[0], pk[1], pk[2], pk[3]);
      }
      // every 4th t: load next coef window into the idle buffer; the epoch
      // barrier separates these writes from next epoch's reads.
      if ((t & 3) == 3 && t + 1 < T_ && wl_on) {
        const int t1 = t + 1;  // multiple of 4
        *(f32x4*)(&CoefW[(t1 >> 2) & 1][0] + wl_dst) =
            *(const f32x4*)(wl_src + (t1 + wl_tw) * 128);
      }
    }
    __syncthreads();  // the ONLY barrier per timestep: e(t) + h(t-1) visible

    // prefetch x(t+1): full compute phase of latency cover
    if (t + 1 < T_) {
#pragma unroll
      for (int r = 0; r < 4; ++r)
        xv4[r] = x2[(size_t)(b0 + rg * 4 + r) * 128 + (t + 1)];
    }

    // deferred cross-wave z-stat flush: ts t-2 from buffer p^1 (written iter t-1)
    if (t >= 2 && tid < 10) {
      const int o = tid >> 1, kind = tid & 1;
      float s = 0.f;
#pragma unroll
      for (int ww = 0; ww < 8; ++ww)
        s += kind ? zredQ[p ^ 1][ww][o] : zredS[p ^ 1][ww][o];
      atomicAdd(&zstats[(size_t)(t - 2) * 10 + o * 2 + kind], s);
    }

    // ---- software-pipelined mt loop: GATE(mt) overlaps EW(mt-1) ----
    f32x4 acc[2][4];
    f32x4 zac = {0.f, 0.f, 0.f, 0.f};
    GATE_TILE(0, 0)
#pragma unroll
    for (int mt = 1; mt < 8; ++mt) {
      GATE_TILE(mt, (mt & 1))
      EW_TILE((mt - 1), ((mt - 1) & 1))
    }
    EW_TILE(7, 1)
  }

  // final z-stat flush: ts T_-1 written at iter T_ into buffer (T_&1)=0
  __syncthreads();
  if (tid < 10) {
    const int o = tid >> 1, kind = tid & 1;
    float s = 0.f;
#pragma unroll
    for (int ww = 0; ww < 8; ++ww) s += kind ? zredQ[0][ww][o] : zredS[0][ww][o];
    atomicAdd(&zstats[(size_t)(T_ - 1) * 10 + o * 2 + kind], s);
  }
}

// ---- kernel 5: in-place output BN + ReLU (verified) ----
__global__ void k_outbn(float* __restrict__ out, const float* __restrict__ zstats,
                        const float* __restrict__ gamma2, const float* __restrict__ beta2) {
  int idx = blockIdx.x * 256 + threadIdx.x;
  int r = idx % 640;
  int t = r / 5, o = r - t * 5;
  float z = out[idx];
  float sum = zstats[t * 10 + o * 2];
  float ss = zstats[t * 10 + o * 2 + 1];
  float mu = sum * (1.f / (float)B_);
  float var = ss * (1.f / (float)B_) - mu * mu;
  float y = gamma2[o] * (z - mu) * rsqrtf(var + EPS_) + beta2[o];
  out[idx] = fmaxf(y, 0.f);
}

extern "C" void kernel_launch(void* const* d_in, const int* in_sizes, int n_in, void* d_out,
                              int out_size, void* d_ws, size_t ws_size, hipStream_t stream) {
  const float* x = (const float*)d_in[0];
  const float* w_emb = (const float*)d_in[1];
  const float* b_emb = (const float*)d_in[2];
  const float* gamma1 = (const float*)d_in[3];
  const float* beta1 = (const float*)d_in[4];
  const float* w_ih = (const float*)d_in[5];
  const float* w_hh = (const float*)d_in[6];
  const float* b_ih = (const float*)d_in[7];
  const float* b_hh = (const float*)d_in[8];
  const float* w_out = (const float*)d_in[9];
  const float* b_out = (const float*)d_in[10];
  const float* gamma2 = (const float*)d_in[11];
  const float* beta2 = (const float*)d_in[12];
  float* out = (float*)d_out;
  float* ws = (float*)d_ws;

  ushort_t* Wc2 = (ushort_t*)(ws + WS_WC2);
  float* gbias = ws + WS_GB;
  float* A0 = ws + WS_A0;
  float* A1 = ws + WS_A1;
  float* C = ws + WS_C;
  float* istats = ws + WS_IST;
  float* zstats = ws + WS_ZST;

  hipMemsetAsync(istats, 0, 640 * sizeof(float), stream);
  hipMemsetAsync(zstats, 0, 1280 * sizeof(float), stream);

  k_istats<<<512, 256, 0, stream>>>(x, istats);
  k_prep_w<<<528, 256, 0, stream>>>(w_ih, w_hh, w_out, b_ih, b_hh, b_out, Wc2, gbias);
  k_coef<<<64, 256, 0, stream>>>(istats, w_emb, b_emb, gamma1, beta1, A0, A1, C);
  k_lstm<<<256, 512, 0, stream>>>(x, Wc2, gbias, A0, A1, C, out, zstats);
  k_outbn<<<(B_ * T_ * OUT_) / 256, 256, 0, stream>>>(out, zstats, gamma2, beta2);
}